// Round 1
// baseline (658.975 us; speedup 1.0000x reference)
//
#include <hip/hip_runtime.h>
#include <math.h>

#define BB 256
#define SS 4096
#define FF 8
#define HH 32
#define TT 128              // timesteps per LDS tile
#define NT (SS/TT)          // 32 tiles
#define NTHREADS 256
#define NG 8                // groups = NTHREADS/HH
#define CL (TT/NG)          // 16 timesteps per group chunk
#define HP 36               // padded LDS row stride (16B aligned, breaks bank patterns)

__global__ __launch_bounds__(NTHREADS, 1)
void forecast_fused(const float* __restrict__ x,
                    const float* __restrict__ Wemb, const float* __restrict__ bemb,
                    const float* __restrict__ Wd,   const float* __restrict__ bd,
                    const float* __restrict__ Alog,
                    const float* __restrict__ Wg,   const float* __restrict__ bg,
                    const float* __restrict__ gmma, const float* __restrict__ beta,
                    const float* __restrict__ W1,   const float* __restrict__ b1,
                    const float* __restrict__ W2,   const float* __restrict__ b2,
                    float* __restrict__ out)
{
    __shared__ float xs[TT * FF];          // staged x tile
    __shared__ float h0s[TT][HP];          // h (block input / output, in place)
    __shared__ float abS[TT][HP];          // abar -> inclusive prefix products
    __shared__ float xiS[TT][HP];          // xin  -> local scan states
    __shared__ float gtS[TT][HP];          // gate (block 1)
    __shared__ float carry[NG][HH];        // per-chunk scan carry-in
    __shared__ float s1s[HH];              // running state, block 1
    __shared__ float s2s[HH];              // running state, block 2
    __shared__ float hns[HH];              // layernorm output

    const int tid = threadIdx.x;
    const int c   = tid & (HH - 1);        // channel
    const int g   = tid >> 5;              // chunk group
    const int b   = blockIdx.x;
    const int ts0 = g * CL;

    // ---- preload weight columns into registers (column c of each matrix) ----
    float we[FF], wd1[HH], wg1[HH], wd2[HH];
#pragma unroll
    for (int f = 0; f < FF; ++f) we[f] = Wemb[f * HH + c];
#pragma unroll
    for (int k = 0; k < HH; ++k) {
        wd1[k] = Wd[k * HH + c];
        wg1[k] = Wg[k * HH + c];
        wd2[k] = Wd[HH * HH + k * HH + c];
    }
    const float bec = bemb[c];
    const float bd1 = bd[c], bg1 = bg[c], bd2 = bd[HH + c];
    const float nA1 = -expf(Alog[c]);
    const float nA2 = -expf(Alog[HH + c]);

    if (tid < HH) { s1s[tid] = 0.f; s2s[tid] = 0.f; }
    __syncthreads();

    for (int it = 0; it < NT; ++it) {
        const int sbase = it * TT;

        // ---- X: stage x tile (coalesced: 256 x float4 = 1024 floats) ----
        const float4* xg = reinterpret_cast<const float4*>(x + ((size_t)b * SS + sbase) * FF);
        reinterpret_cast<float4*>(xs)[tid] = xg[tid];
        __syncthreads();

        // ---- E: embed h0 = x @ Wemb + bemb ----
        for (int r = 0; r < CL; ++r) {
            const int ts = ts0 + r;
            float acc = bec;
#pragma unroll
            for (int f = 0; f < FF; ++f) acc += xs[ts * FF + f] * we[f];
            h0s[ts][c] = acc;
        }
        __syncthreads();

        // ---- D1: delta/abar/xin/gate for block 1 (shared row reads) ----
        for (int r = 0; r < CL; ++r) {
            const int ts = ts0 + r;
            float zd = bd1, zg = bg1;
#pragma unroll
            for (int k = 0; k < HH; k += 4) {
                const float4 hv = *reinterpret_cast<const float4*>(&h0s[ts][k]);
                zd += hv.x * wd1[k] + hv.y * wd1[k+1] + hv.z * wd1[k+2] + hv.w * wd1[k+3];
                zg += hv.x * wg1[k] + hv.y * wg1[k+1] + hv.z * wg1[k+2] + hv.w * wg1[k+3];
            }
            const float delta = fmaxf(zd, 0.f) + log1pf(expf(-fabsf(zd)));
            const float ab = expf(delta * nA1);
            const float hh = h0s[ts][c];
            const float gt = 1.0f / (1.0f + expf(-zg));
            abS[ts][c] = ab;
            xiS[ts][c] = delta * hh;
            gtS[ts][c] = gt;
        }
        __syncthreads();

        // ---- A1: chunk-local scan (in place: xiS<-local state, abS<-prefix prod) ----
        {
            float p = 1.f, sl = 0.f;
            for (int r = 0; r < CL; ++r) {
                const int ts = ts0 + r;
                const float a  = abS[ts][c];
                const float xv = xiS[ts][c];
                sl = a * sl + xv;
                p *= a;
                xiS[ts][c] = sl;
                abS[ts][c] = p;
            }
        }
        __syncthreads();

        // ---- B1: cross-chunk carries (32 threads) ----
        if (tid < HH) {
            float cy = s1s[tid];
#pragma unroll
            for (int ch = 0; ch < NG; ++ch) {
                carry[ch][tid] = cy;
                const float A = abS[ch * CL + CL - 1][tid];
                const float X = xiS[ch * CL + CL - 1][tid];
                cy = A * cy + X;
            }
            s1s[tid] = cy;
        }
        __syncthreads();

        // ---- C1+H1: fixup states and apply residual gate: h1 = h0 + s*gate ----
        {
            const float cin = carry[g][c];
            for (int r = 0; r < CL; ++r) {
                const int ts = ts0 + r;
                const float st = xiS[ts][c] + abS[ts][c] * cin;
                h0s[ts][c] = h0s[ts][c] + st * gtS[ts][c];
            }
        }
        __syncthreads();

        // ---- D2: delta/abar/xin for block 2 (no gate except last token) ----
        for (int r = 0; r < CL; ++r) {
            const int ts = ts0 + r;
            float zd = bd2;
#pragma unroll
            for (int k = 0; k < HH; k += 4) {
                const float4 hv = *reinterpret_cast<const float4*>(&h0s[ts][k]);
                zd += hv.x * wd2[k] + hv.y * wd2[k+1] + hv.z * wd2[k+2] + hv.w * wd2[k+3];
            }
            const float delta = fmaxf(zd, 0.f) + log1pf(expf(-fabsf(zd)));
            const float ab = expf(delta * nA2);
            const float hh = h0s[ts][c];
            abS[ts][c] = ab;
            xiS[ts][c] = delta * hh;
        }
        __syncthreads();

        // ---- A2: chunk-local scan ----
        {
            float p = 1.f, sl = 0.f;
            for (int r = 0; r < CL; ++r) {
                const int ts = ts0 + r;
                const float a  = abS[ts][c];
                const float xv = xiS[ts][c];
                sl = a * sl + xv;
                p *= a;
                xiS[ts][c] = sl;
                abS[ts][c] = p;
            }
        }
        __syncthreads();

        // ---- B2: carry only (states2 never materialized) ----
        if (tid < HH) {
            float cy = s2s[tid];
#pragma unroll
            for (int ch = 0; ch < NG; ++ch) {
                const float A = abS[ch * CL + CL - 1][tid];
                const float X = xiS[ch * CL + CL - 1][tid];
                cy = A * cy + X;
            }
            s2s[tid] = cy;
        }
        __syncthreads();
    }

    // ---- head: gate2 @ last token, residual, LN, GELU MLP -> scalar ----
    if (tid < HH) {
        float zg = bg[HH + tid];
#pragma unroll
        for (int k = 0; k < HH; ++k) zg += h0s[TT - 1][k] * Wg[HH * HH + k * HH + tid];
        const float gt = 1.0f / (1.0f + expf(-zg));
        const float h2 = h0s[TT - 1][tid] + s2s[tid] * gt;

        float sum = h2;
#pragma unroll
        for (int m = 1; m < HH; m <<= 1) sum += __shfl_xor(sum, m);
        const float mu = sum * (1.0f / HH);
        const float d  = h2 - mu;
        float vs = d * d;
#pragma unroll
        for (int m = 1; m < HH; m <<= 1) vs += __shfl_xor(vs, m);
        const float var  = vs * (1.0f / HH);
        const float rstd = 1.0f / sqrtf(var + 1e-5f);
        hns[tid] = d * rstd * gmma[tid] + beta[tid];
    }
    __syncthreads();
    if (tid < HH) {
        float z = b1[tid];
#pragma unroll
        for (int k = 0; k < HH; ++k) z += hns[k] * W1[k * HH + tid];
        const float u  = 0.7978845608028654f * (z + 0.044715f * z * z * z);
        const float ge = 0.5f * z * (1.0f + tanhf(u));
        float v = ge * W2[tid];
#pragma unroll
        for (int m = 1; m < HH; m <<= 1) v += __shfl_xor(v, m);
        if (tid == 0) out[b] = v + b2[0];
    }
}

extern "C" void kernel_launch(void* const* d_in, const int* in_sizes, int n_in,
                              void* d_out, int out_size, void* d_ws, size_t ws_size,
                              hipStream_t stream) {
    const float* x    = (const float*)d_in[0];
    const float* Wemb = (const float*)d_in[1];
    const float* bemb = (const float*)d_in[2];
    const float* Wd   = (const float*)d_in[3];
    const float* bd   = (const float*)d_in[4];
    const float* Alog = (const float*)d_in[5];
    const float* Wg   = (const float*)d_in[6];
    const float* bg   = (const float*)d_in[7];
    const float* gmma = (const float*)d_in[8];
    const float* beta = (const float*)d_in[9];
    const float* W1   = (const float*)d_in[10];
    const float* b1   = (const float*)d_in[11];
    const float* W2   = (const float*)d_in[12];
    const float* b2   = (const float*)d_in[13];
    float* out = (float*)d_out;

    forecast_fused<<<dim3(BB), dim3(NTHREADS), 0, stream>>>(
        x, Wemb, bemb, Wd, bd, Alog, Wg, bg, gmma, beta, W1, b1, W2, b2, out);
}